// Round 4
// baseline (8679.505 us; speedup 1.0000x reference)
//
#include <hip/hip_runtime.h>
#include <math.h>

#define BB 64
#define TT 128
#define SS 256
#define HHH 1024
#define NBLK 256

typedef unsigned short u16;
typedef __bf16 bf16x8 __attribute__((ext_vector_type(8)));
typedef float f32x4 __attribute__((ext_vector_type(4)));
typedef u16 u16x8 __attribute__((ext_vector_type(8)));

__device__ __forceinline__ float sigmoidf_(float x) { return 1.0f / (1.0f + expf(-x)); }
__device__ __forceinline__ u16 f2bf(float f) {
    __bf16 h = (__bf16)f;
    return __builtin_bit_cast(u16, h);
}
__device__ __forceinline__ float b2f(u16 u) {
    return __builtin_bit_cast(float, (unsigned)u << 16);
}
template <typename OT>
__device__ __forceinline__ void stout(OT* p, float v) {
    if constexpr (sizeof(OT) == 2) *p = f2bf(v); else *p = v;
}

// ---------------------------------------------------------------------------
// fp32 → bf16 elementwise
// ---------------------------------------------------------------------------
__global__ __launch_bounds__(256) void f32_to_bf16(const float* __restrict__ in,
                                                   u16* __restrict__ out, long n) {
    long i = ((long)blockIdx.x * 256 + threadIdx.x) * 8;
    float4 a = *(const float4*)(in + i);
    float4 b = *(const float4*)(in + i + 4);
    u16x8 o;
    o[0] = f2bf(a.x); o[1] = f2bf(a.y); o[2] = f2bf(a.z); o[3] = f2bf(a.w);
    o[4] = f2bf(b.x); o[5] = f2bf(b.y); o[6] = f2bf(b.z); o[7] = f2bf(b.w);
    *(u16x8*)(out + i) = o;
}

// ---------------------------------------------------------------------------
// h0 [64 b][1024 j] -> hb [1024 j][64 b]  (grid 16, 256 thr)
// ---------------------------------------------------------------------------
__global__ __launch_bounds__(256) void transpose_h0(const float* __restrict__ h0,
                                                    float* __restrict__ ht) {
    __shared__ float tl[64][68];
    const int j0t = blockIdx.x << 6;
    const int tid = threadIdx.x;
    {
        int b = tid >> 2, q4 = (tid & 3) << 4;
#pragma unroll
        for (int q = 0; q < 4; ++q) {
            float4 v = *(const float4*)(h0 + (size_t)b * 1024 + j0t + q4 + q * 4);
            tl[b][q4 + q * 4 + 0] = v.x; tl[b][q4 + q * 4 + 1] = v.y;
            tl[b][q4 + q * 4 + 2] = v.z; tl[b][q4 + q * 4 + 3] = v.w;
        }
    }
    __syncthreads();
    int j = tid >> 2, b4 = (tid & 3) << 4;
#pragma unroll
    for (int q = 0; q < 4; ++q) {
        float4 v = { tl[b4 + q * 4 + 0][j], tl[b4 + q * 4 + 1][j],
                     tl[b4 + q * 4 + 2][j], tl[b4 + q * 4 + 3][j] };
        *(float4*)(ht + (size_t)(j0t + j) * 64 + b4 + q * 4) = v;
    }
}

// ---------------------------------------------------------------------------
// MFMA bf16 GEMM (A@B^T), XGT mode writes fp32-transposed xgt[t][4H][B]+bias.
// ---------------------------------------------------------------------------
template <bool TANH, bool XGT, typename OT>
__global__ __launch_bounds__(256) void gemm_mfma_bt(
    const u16* __restrict__ A0, const u16* __restrict__ A1,
    const u16* __restrict__ B, OT* __restrict__ C,
    int M, int N, int K, int KA0,
    const float* __restrict__ bias0, const float* __restrict__ bias1)
{
    __shared__ uint4 As4[512];
    __shared__ uint4 Bs4[512];
    u16* As = (u16*)As4;
    u16* Bs = (u16*)Bs4;
    const int tid = threadIdx.x;
    const int l = tid & 63;
    const int w = tid >> 6;
    const int wm = w >> 1, wn = w & 1;
    const int tc = l & 15, tr8 = (l >> 4) << 3;
    const int m0 = blockIdx.y << 7, n0 = blockIdx.x << 7;
    f32x4 acc[4][4] = {};

    for (int k0 = 0; k0 < K; k0 += 32) {
        const u16* Ap = (k0 < KA0) ? A0 : A1;
        const int koff = (k0 < KA0) ? k0 : k0 - KA0;
#pragma unroll
        for (int r = 0; r < 2; ++r) {
            int u = tid + (r << 8);
            int row = u >> 2, q = u & 3;
            size_t arow;
            if (XGT) {
                int rr = m0 + row;
                arow = (size_t)((rr & 63) * 128 + (rr >> 6));
            } else {
                arow = (size_t)(m0 + row);
            }
            As4[u] = *(const uint4*)(Ap + arow * KA0 + koff + (q << 3));
            Bs4[u] = *(const uint4*)(B + (size_t)(n0 + row) * K + k0 + (q << 3));
        }
        __syncthreads();
        bf16x8 bfr[4];
#pragma unroll
        for (int j = 0; j < 4; ++j)
            bfr[j] = *(const bf16x8*)(Bs + ((wn << 6) + (j << 4) + tc) * 32 + tr8);
#pragma unroll
        for (int i = 0; i < 4; ++i) {
            bf16x8 af = *(const bf16x8*)(As + ((wm << 6) + (i << 4) + tc) * 32 + tr8);
#pragma unroll
            for (int j = 0; j < 4; ++j)
                acc[i][j] = __builtin_amdgcn_mfma_f32_16x16x32_bf16(af, bfr[j], acc[i][j], 0, 0, 0);
        }
        __syncthreads();
    }
#pragma unroll
    for (int j = 0; j < 4; ++j) {
        const int col = n0 + (wn << 6) + (j << 4) + tc;
        const float bias = XGT ? (bias0[col] + bias1[col]) : 0.0f;
#pragma unroll
        for (int i = 0; i < 4; ++i) {
#pragma unroll
            for (int v = 0; v < 4; ++v) {
                int r = m0 + (wm << 6) + (i << 4) + ((l >> 4) << 2) + v;
                float val = acc[i][j][v];
                if (XGT) {
                    ((float*)C)[(size_t)(r >> 6) * 262144 + (size_t)col * 64 + (r & 63)] = val + bias;
                } else {
                    if (TANH) val = tanhf(val);
                    stout(&C[(size_t)r * N + col], val);
                }
            }
        }
    }
}

// ---------------------------------------------------------------------------
// Grid-wide barrier (sense-reversing, device-scope atomics).
// Requires all NBLK blocks co-resident (grid == CU count, 1 block/CU).
// ---------------------------------------------------------------------------
__device__ __forceinline__ void grid_sync(int* cnt, int* gen) {
    __syncthreads();
    if (threadIdx.x == 0) {
        __threadfence();   // release: flush this XCD's dirty lines
        int g = __hip_atomic_load(gen, __ATOMIC_RELAXED, __HIP_MEMORY_SCOPE_AGENT);
        int arrived = __hip_atomic_fetch_add(cnt, 1, __ATOMIC_ACQ_REL, __HIP_MEMORY_SCOPE_AGENT);
        if (arrived == NBLK - 1) {
            __hip_atomic_store(cnt, 0, __ATOMIC_RELAXED, __HIP_MEMORY_SCOPE_AGENT);
            __hip_atomic_store(gen, g + 1, __ATOMIC_RELEASE, __HIP_MEMORY_SCOPE_AGENT);
        } else {
            while (__hip_atomic_load(gen, __ATOMIC_RELAXED, __HIP_MEMORY_SCOPE_AGENT) == g) {
                __builtin_amdgcn_s_sleep(2);
            }
        }
        __threadfence();   // acquire: invalidate stale lines before next step's reads
    }
    __syncthreads();
}

// ---------------------------------------------------------------------------
// Persistent LSTM scan: 256 blocks x 256 thr, 128 steps inside.
// Block owns 4 j (16 W_hh rows) for all 64 b; W_hh slice lives in LDS for the
// whole kernel; h ping-pongs between two [1024 j][64 b] global buffers with a
// grid barrier per step; per-thread c in a register.
// ---------------------------------------------------------------------------
__global__ __launch_bounds__(256) void lstm_scan(
    const float* __restrict__ xgt, const float* __restrict__ W_hh,
    const float* __restrict__ c0,
    float* __restrict__ bufE, float* __restrict__ bufO,
    float* __restrict__ hT, float* __restrict__ cT,
    u16* __restrict__ lstm16,
    int* bar_cnt, int* bar_gen)
{
    __shared__ float Wlds[1024][16];   // [k][row], 64 KB
    __shared__ float hs[4][32][68];    // wave-private h chunk [k][b]
    __shared__ float red[4][1032];
    const int bid = blockIdx.x;
    const int j0 = (((bid & 7) << 5) | (bid >> 3)) << 2;   // XCD-grouped j
    const int tid = threadIdx.x;
    const int kg = tid >> 6;           // wave id = K-quarter = epilogue jj
    const int l = tid & 63;            // lane = epilogue b
    const int tr = l >> 4, tc = l & 15;
    const int kbase = kg << 8;
    const int krow0 = l >> 4;          // 0..3
    const int b4 = (l & 15) << 2;      // 0..60

    // ---- W_hh slice -> LDS once (rows: g=row>>2, jj=row&3)
    for (int i = tid; i < 16 * 256; i += 256) {
        int row = i >> 8;
        int k4 = (i & 255) << 2;
        int g = row >> 2, jj = row & 3;
        float4 v = *(const float4*)(W_hh + (size_t)(g * 1024 + j0 + jj) * 1024 + k4);
        Wlds[k4 + 0][row] = v.x; Wlds[k4 + 1][row] = v.y;
        Wlds[k4 + 2][row] = v.z; Wlds[k4 + 3][row] = v.w;
    }
    float creg = c0[(size_t)l * 1024 + j0 + kg];
    __syncthreads();

    for (int t = 0; t < 128; ++t) {
        const float* hin = (t & 1) ? bufO : bufE;
        float* hout      = (t & 1) ? bufE : bufO;

        // prefetch this step's xg gate values (independent of h)
        float xgv[4];
#pragma unroll
        for (int g = 0; g < 4; ++g)
            xgv[g] = xgt[(size_t)t * 262144 + (size_t)(g * 1024 + j0 + kg) * 64 + l];

        float acc[4][4] = {};
        float4 hv[8];
#pragma unroll
        for (int r = 0; r < 8; ++r)
            hv[r] = *(const float4*)(hin + (size_t)(kbase + r * 4 + krow0) * 64 + b4);

        for (int ch = 0; ch < 8; ++ch) {
#pragma unroll
            for (int r = 0; r < 8; ++r)
                *(float4*)&hs[kg][r * 4 + krow0][b4] = hv[r];
            if (ch < 7) {
                const int k0 = kbase + (ch + 1) * 32;
#pragma unroll
                for (int r = 0; r < 8; ++r)
                    hv[r] = *(const float4*)(hin + (size_t)(k0 + r * 4 + krow0) * 64 + b4);
            }
#pragma unroll
            for (int kk = 0; kk < 32; ++kk) {
                const int kglob = kbase + ch * 32 + kk;
                float4 h4 = *(const float4*)&hs[kg][kk][tc * 4];
                float4 w4 = *(const float4*)&Wlds[kglob][tr * 4];
                float hh[4] = {h4.x, h4.y, h4.z, h4.w};
                float ww[4] = {w4.x, w4.y, w4.z, w4.w};
#pragma unroll
                for (int i = 0; i < 4; ++i)
#pragma unroll
                    for (int j = 0; j < 4; ++j)
                        acc[i][j] += ww[i] * hh[j];
            }
        }
#pragma unroll
        for (int i = 0; i < 4; ++i)
#pragma unroll
            for (int j = 0; j < 4; ++j)
                red[kg][(tr * 4 + i) * 64 + tc * 4 + j] = acc[i][j];
        __syncthreads();

        // epilogue: thread -> (b=l, jj=kg)
        float gate[4];
#pragma unroll
        for (int g = 0; g < 4; ++g) {
            int r = g * 4 + kg;
            gate[g] = red[0][r * 64 + l] + red[1][r * 64 + l] +
                      red[2][r * 64 + l] + red[3][r * 64 + l] + xgv[g];
        }
        float ii = sigmoidf_(gate[0]);
        float ff = sigmoidf_(gate[1]);
        float gg = tanhf(gate[2]);
        float oo = sigmoidf_(gate[3]);
        creg = ff * creg + ii * gg;
        float hn = oo * tanhf(creg);
        hout[(size_t)(j0 + kg) * 64 + l] = hn;
        lstm16[((size_t)l * 128 + t) * 1024 + j0 + kg] = f2bf(hn);
        if (t == 127) hT[(size_t)l * 1024 + j0 + kg] = hn;

        if (t < 127) grid_sync(bar_cnt, bar_gen);
    }
    cT[(size_t)l * 1024 + j0 + kg] = creg;
}

// ---------------------------------------------------------------------------
// fp32 GEMM C = A @ B^T (scores), batched via blockIdx.z.
// ---------------------------------------------------------------------------
template <int BM, int BN, int TM, int TN>
__global__ __launch_bounds__(256) void gemm_bt(
    const float* __restrict__ A, const float* __restrict__ Bm, float* __restrict__ C,
    int M, int N, int K, long sA, long sB, long sC)
{
    constexpr int BK = 16;
    __shared__ float As[BK][BM + 1];
    __shared__ float Bs[BK][BN + 1];
    const int z = blockIdx.z;
    A += (long)z * sA; Bm += (long)z * sB; C += (long)z * sC;
    const int bm = blockIdx.y * BM, bn = blockIdx.x * BN;
    const int tid = threadIdx.x;
    constexpr int TC = BN / TN;
    const int tc = tid % TC, tr = tid / TC;
    float acc[TM][TN] = {};
    for (int k0 = 0; k0 < K; k0 += BK) {
        for (int i = tid; i < BM * 4; i += 256) {
            int m = i >> 2, k4 = (i & 3) << 2;
            float4 v = *(const float4*)(A + (long)(bm + m) * K + k0 + k4);
            As[k4][m] = v.x; As[k4 + 1][m] = v.y; As[k4 + 2][m] = v.z; As[k4 + 3][m] = v.w;
        }
        for (int i = tid; i < BN * 4; i += 256) {
            int n = i >> 2, k4 = (i & 3) << 2;
            float4 v = *(const float4*)(Bm + (long)(bn + n) * K + k0 + k4);
            Bs[k4][n] = v.x; Bs[k4 + 1][n] = v.y; Bs[k4 + 2][n] = v.z; Bs[k4 + 3][n] = v.w;
        }
        __syncthreads();
#pragma unroll
        for (int kk = 0; kk < BK; ++kk) {
            float a[TM], b[TN];
#pragma unroll
            for (int i = 0; i < TM; i++) a[i] = As[kk][tr * TM + i];
#pragma unroll
            for (int j = 0; j < TN; j++) b[j] = Bs[kk][tc * TN + j];
#pragma unroll
            for (int i = 0; i < TM; i++)
#pragma unroll
                for (int j = 0; j < TN; j++) acc[i][j] += a[i] * b[j];
        }
        __syncthreads();
    }
#pragma unroll
    for (int i = 0; i < TM; i++) {
        int m = bm + tr * TM + i;
#pragma unroll
        for (int j = 0; j < TN; j++) {
            int n = bn + tc * TN + j;
            C[(long)m * N + n] = acc[i][j];
        }
    }
}

// ---------------------------------------------------------------------------
// fp32 GEMM C = A @ B (context = attn @ ctx), OT output.
// ---------------------------------------------------------------------------
template <int BM, int BN, int TM, int TN, typename OT>
__global__ __launch_bounds__(256) void gemm_bn(
    const float* __restrict__ A, const float* __restrict__ Bm, OT* __restrict__ C,
    int M, int N, int K, long sA, long sB, long sC)
{
    constexpr int BK = 16;
    __shared__ float As[BK][BM + 1];
    __shared__ float Bs[BK][BN + 1];
    const int z = blockIdx.z;
    A += (long)z * sA; Bm += (long)z * sB; C += (long)z * sC;
    const int bm = blockIdx.y * BM, bn = blockIdx.x * BN;
    const int tid = threadIdx.x;
    constexpr int TC = BN / TN;
    const int tc = tid % TC, tr = tid / TC;
    float acc[TM][TN] = {};
    for (int k0 = 0; k0 < K; k0 += BK) {
        for (int i = tid; i < BM * 4; i += 256) {
            int m = i >> 2, k4 = (i & 3) << 2;
            float4 v = *(const float4*)(A + (long)(bm + m) * K + k0 + k4);
            As[k4][m] = v.x; As[k4 + 1][m] = v.y; As[k4 + 2][m] = v.z; As[k4 + 3][m] = v.w;
        }
        for (int i = tid; i < BK * (BN / 4); i += 256) {
            int k = i / (BN / 4), n4 = (i % (BN / 4)) * 4;
            float4 v = *(const float4*)(Bm + (long)(k0 + k) * N + bn + n4);
            Bs[k][n4] = v.x; Bs[k][n4 + 1] = v.y; Bs[k][n4 + 2] = v.z; Bs[k][n4 + 3] = v.w;
        }
        __syncthreads();
#pragma unroll
        for (int kk = 0; kk < BK; ++kk) {
            float a[TM], b[TN];
#pragma unroll
            for (int i = 0; i < TM; i++) a[i] = As[kk][tr * TM + i];
#pragma unroll
            for (int j = 0; j < TN; j++) b[j] = Bs[kk][tc * TN + j];
#pragma unroll
            for (int i = 0; i < TM; i++)
#pragma unroll
                for (int j = 0; j < TN; j++) acc[i][j] += a[i] * b[j];
        }
        __syncthreads();
    }
#pragma unroll
    for (int i = 0; i < TM; i++) {
        int m = bm + tr * TM + i;
#pragma unroll
        for (int j = 0; j < TN; j++) {
            int n = bn + tc * TN + j;
            stout(&C[(long)m * N + n], acc[i][j]);
        }
    }
}

// ---------------------------------------------------------------------------
// Masked softmax over S=256, in place.
// ---------------------------------------------------------------------------
__global__ __launch_bounds__(256) void softmax_mask(
    float* __restrict__ attn, const int* __restrict__ src_len)
{
    __shared__ float red[4];
    const int b = blockIdx.y, t = blockIdx.x, s = threadIdx.x;
    float* row = attn + ((long)b * TT + t) * SS;
    const int L = src_len[b];
    float v = (s < L) ? row[s] : -INFINITY;
    float m = v;
#pragma unroll
    for (int o = 32; o >= 1; o >>= 1) m = fmaxf(m, __shfl_xor(m, o));
    if ((s & 63) == 0) red[s >> 6] = m;
    __syncthreads();
    m = fmaxf(fmaxf(red[0], red[1]), fmaxf(red[2], red[3]));
    __syncthreads();
    float e = (s < L) ? expf(v - m) : 0.0f;
    float sum = e;
#pragma unroll
    for (int o = 32; o >= 1; o >>= 1) sum += __shfl_xor(sum, o);
    if ((s & 63) == 0) red[s >> 6] = sum;
    __syncthreads();
    sum = red[0] + red[1] + red[2] + red[3];
    row[s] = e / sum;
}

// ---------------------------------------------------------------------------
extern "C" void kernel_launch(void* const* d_in, const int* in_sizes, int n_in,
                              void* d_out, int out_size, void* d_ws, size_t ws_size,
                              hipStream_t stream)
{
    const float* trg_emb = (const float*)d_in[0];
    const float* h0      = (const float*)d_in[1];
    const float* c0      = (const float*)d_in[2];
    const float* ctx     = (const float*)d_in[3];
    const int*   src_len = (const int*)d_in[4];
    const float* W_ih    = (const float*)d_in[5];
    const float* W_hh    = (const float*)d_in[6];
    const float* b_ih    = (const float*)d_in[7];
    const float* b_hh    = (const float*)d_in[8];
    const float* W_in    = (const float*)d_in[9];
    const float* W_out   = (const float*)d_in[10];

    float* out = (float*)d_out;
    float* h_tilde = out;                          // [B,T,H]
    float* hT = out + (size_t)BB * TT * HHH;       // [1,B,H]
    float* cT = hT + (size_t)BB * HHH;             // [1,B,H]

    char* w = (char*)d_ws;
    auto take = [&](size_t bytes) { void* p = w; w += (bytes + 255) & ~(size_t)255; return p; };
    u16* trg16  = (u16*)take(8388608ull * 2);
    u16* Wih16  = (u16*)take(4194304ull * 2);
    u16* Win16  = (u16*)take(1048576ull * 2);
    u16* Wout16 = (u16*)take(2097152ull * 2);
    u16* lstm16 = (u16*)take(8388608ull * 2);
    float* bufE = (float*)take(65536ull * 4);      // h ping-pong [j][b]
    float* bufO = (float*)take(65536ull * 4);
    int* bar    = (int*)take(256);                 // [0]=cnt, [1]=gen
    char* regionB = w;
    float* xgt = (float*)take(33554432ull * 4);    // [t][4H][B] fp32, bias folded
    float* q        = (float*)regionB;
    float* attn     = (float*)(regionB + 33554432ull);
    u16*   ctxout16 = (u16*)(regionB + 41943040ull);

    // barrier state must be zeroed every call (ws is poisoned before timing)
    hipMemsetAsync(bar, 0, 256, stream);

    f32_to_bf16<<<4096, 256, 0, stream>>>(trg_emb, trg16, 8388608);
    f32_to_bf16<<<2048, 256, 0, stream>>>(W_ih, Wih16, 4194304);
    f32_to_bf16<<<512, 256, 0, stream>>>(W_in, Win16, 1048576);
    f32_to_bf16<<<1024, 256, 0, stream>>>(W_out, Wout16, 2097152);

    // x_gates = trg_emb @ W_ih^T + (b_ih+b_hh), fp32-transposed to xgt[t][4H][B]
    gemm_mfma_bt<false, true, float><<<dim3(32, 64), 256, 0, stream>>>(
        trg16, trg16, Wih16, xgt, 8192, 4096, 1024, 1024, b_ih, b_hh);

    // h0 -> [j][b]
    transpose_h0<<<16, 256, 0, stream>>>(h0, bufE);

    // persistent scan (writes lstm16, hT, cT)
    lstm_scan<<<NBLK, 256, 0, stream>>>(xgt, W_hh, c0, bufE, bufO, hT, cT,
                                        lstm16, bar, bar + 1);

    // q = lstm_out @ W_in^T (bf16 MFMA, fp32 out)
    gemm_mfma_bt<false, false, float><<<dim3(8, 64), 256, 0, stream>>>(
        lstm16, lstm16, Win16, q, 8192, 1024, 1024, 1024, nullptr, nullptr);

    // scores[b] = q[b] @ ctx[b]^T (fp32)
    gemm_bt<64, 64, 4, 4><<<dim3(4, 2, 64), 256, 0, stream>>>(
        q, ctx, attn, TT, SS, HHH,
        (long)TT * HHH, (long)SS * HHH, (long)TT * SS);

    softmax_mask<<<dim3(TT, BB, 1), 256, 0, stream>>>(attn, src_len);

    // context[b] = attn[b] @ ctx[b] (fp32 compute, bf16 out)
    gemm_bn<64, 64, 4, 4, u16><<<dim3(16, 2, 64), 256, 0, stream>>>(
        attn, ctx, ctxout16, TT, HHH, SS,
        (long)TT * SS, (long)SS * HHH, (long)TT * HHH);

    // h_tilde = tanh([context, lstm_out] @ W_out^T)
    gemm_mfma_bt<true, false, float><<<dim3(8, 64), 256, 0, stream>>>(
        ctxout16, lstm16, Wout16, h_tilde, 8192, 1024, 2048, 1024, nullptr, nullptr);
}

// Round 5
// 2592.843 us; speedup vs baseline: 3.3475x; 3.3475x over previous
//
#include <hip/hip_runtime.h>
#include <math.h>

#define BB 64
#define TT 128
#define SS 256
#define HHH 1024

typedef unsigned short u16;
typedef __bf16 bf16x8 __attribute__((ext_vector_type(8)));
typedef float f32x4 __attribute__((ext_vector_type(4)));
typedef u16 u16x8 __attribute__((ext_vector_type(8)));

__device__ __forceinline__ float sigmoidf_(float x) { return 1.0f / (1.0f + expf(-x)); }
__device__ __forceinline__ u16 f2bf(float f) {
    __bf16 h = (__bf16)f;
    return __builtin_bit_cast(u16, h);
}
__device__ __forceinline__ float b2f(u16 u) {
    return __builtin_bit_cast(float, (unsigned)u << 16);
}
template <typename OT>
__device__ __forceinline__ void stout(OT* p, float v) {
    if constexpr (sizeof(OT) == 2) *p = f2bf(v); else *p = v;
}

// ---------------------------------------------------------------------------
// fp32 → bf16 elementwise
// ---------------------------------------------------------------------------
__global__ __launch_bounds__(256) void f32_to_bf16(const float* __restrict__ in,
                                                   u16* __restrict__ out, long n) {
    long i = ((long)blockIdx.x * 256 + threadIdx.x) * 8;
    float4 a = *(const float4*)(in + i);
    float4 b = *(const float4*)(in + i + 4);
    u16x8 o;
    o[0] = f2bf(a.x); o[1] = f2bf(a.y); o[2] = f2bf(a.z); o[3] = f2bf(a.w);
    o[4] = f2bf(b.x); o[5] = f2bf(b.y); o[6] = f2bf(b.z); o[7] = f2bf(b.w);
    *(u16x8*)(out + i) = o;
}

// ---------------------------------------------------------------------------
// W_hh [row=g*1024+j][1024] fp32 -> Whi/Wlo bf16 [row'=j*4+g][1024]
// (split precision: W = Whi + Wlo, each bf16; gate rows interleaved per j)
// ---------------------------------------------------------------------------
__global__ __launch_bounds__(256) void split_whh(const float* __restrict__ W,
                                                 u16* __restrict__ hi,
                                                 u16* __restrict__ lo) {
    const int row = blockIdx.x;            // 0..4095 source row
    const int g = row >> 10, j = row & 1023;
    const int dst = (j << 2) | g;
    const int k4 = threadIdx.x << 2;
    float4 v = *(const float4*)(W + (size_t)row * 1024 + k4);
    u16 h0 = f2bf(v.x), h1 = f2bf(v.y), h2 = f2bf(v.z), h3 = f2bf(v.w);
    ushort4 hv = {h0, h1, h2, h3};
    ushort4 lv = {f2bf(v.x - b2f(h0)), f2bf(v.y - b2f(h1)),
                  f2bf(v.z - b2f(h2)), f2bf(v.w - b2f(h3))};
    *(ushort4*)(hi + (size_t)dst * 1024 + k4) = hv;
    *(ushort4*)(lo + (size_t)dst * 1024 + k4) = lv;
}

// ---------------------------------------------------------------------------
// h0 [64 b][1024 j] fp32 -> hhi/hlo bf16 (same [b][j] layout)
// ---------------------------------------------------------------------------
__global__ __launch_bounds__(256) void h0_split(const float* __restrict__ h0,
                                                u16* __restrict__ hi,
                                                u16* __restrict__ lo) {
    long i = ((long)blockIdx.x * 256 + threadIdx.x) * 4;
    float4 v = *(const float4*)(h0 + i);
    u16 a0 = f2bf(v.x), a1 = f2bf(v.y), a2 = f2bf(v.z), a3 = f2bf(v.w);
    ushort4 hv = {a0, a1, a2, a3};
    ushort4 lv = {f2bf(v.x - b2f(a0)), f2bf(v.y - b2f(a1)),
                  f2bf(v.z - b2f(a2)), f2bf(v.w - b2f(a3))};
    *(ushort4*)(hi + i) = hv;
    *(ushort4*)(lo + i) = lv;
}

// ---------------------------------------------------------------------------
// c0 [64 b][1024 j] -> cws [1024 j][64 b] (once)
// ---------------------------------------------------------------------------
__global__ __launch_bounds__(256) void transpose_c0(const float* __restrict__ c0,
                                                    float* __restrict__ cws) {
    int j = blockIdx.x * 4 + (threadIdx.x >> 6);
    int b = threadIdx.x & 63;
    cws[j * 64 + b] = c0[(size_t)b * 1024 + j];
}

// ---------------------------------------------------------------------------
// MFMA bf16 GEMM (A@B^T). XGT mode: logical A row r=t*64+b (phys (r&63)*128+(r>>6));
// C written fp32 to xgt[t][r'=j*4+g][b] with (b_ih+b_hh) folded.
// ---------------------------------------------------------------------------
template <bool TANH, bool XGT, typename OT>
__global__ __launch_bounds__(256) void gemm_mfma_bt(
    const u16* __restrict__ A0, const u16* __restrict__ A1,
    const u16* __restrict__ B, OT* __restrict__ C,
    int M, int N, int K, int KA0,
    const float* __restrict__ bias0, const float* __restrict__ bias1)
{
    __shared__ uint4 As4[512];
    __shared__ uint4 Bs4[512];
    u16* As = (u16*)As4;
    u16* Bs = (u16*)Bs4;
    const int tid = threadIdx.x;
    const int l = tid & 63;
    const int w = tid >> 6;
    const int wm = w >> 1, wn = w & 1;
    const int tc = l & 15, tr8 = (l >> 4) << 3;
    const int m0 = blockIdx.y << 7, n0 = blockIdx.x << 7;
    f32x4 acc[4][4] = {};

    for (int k0 = 0; k0 < K; k0 += 32) {
        const u16* Ap = (k0 < KA0) ? A0 : A1;
        const int koff = (k0 < KA0) ? k0 : k0 - KA0;
#pragma unroll
        for (int r = 0; r < 2; ++r) {
            int u = tid + (r << 8);
            int row = u >> 2, q = u & 3;
            size_t arow;
            if (XGT) {
                int rr = m0 + row;
                arow = (size_t)((rr & 63) * 128 + (rr >> 6));
            } else {
                arow = (size_t)(m0 + row);
            }
            As4[u] = *(const uint4*)(Ap + arow * KA0 + koff + (q << 3));
            Bs4[u] = *(const uint4*)(B + (size_t)(n0 + row) * K + k0 + (q << 3));
        }
        __syncthreads();
        bf16x8 bfr[4];
#pragma unroll
        for (int j = 0; j < 4; ++j)
            bfr[j] = *(const bf16x8*)(Bs + ((wn << 6) + (j << 4) + tc) * 32 + tr8);
#pragma unroll
        for (int i = 0; i < 4; ++i) {
            bf16x8 af = *(const bf16x8*)(As + ((wm << 6) + (i << 4) + tc) * 32 + tr8);
#pragma unroll
            for (int j = 0; j < 4; ++j)
                acc[i][j] = __builtin_amdgcn_mfma_f32_16x16x32_bf16(af, bfr[j], acc[i][j], 0, 0, 0);
        }
        __syncthreads();
    }
#pragma unroll
    for (int j = 0; j < 4; ++j) {
        const int col = n0 + (wn << 6) + (j << 4) + tc;
        const float bias = XGT ? (bias0[col] + bias1[col]) : 0.0f;
#pragma unroll
        for (int i = 0; i < 4; ++i) {
#pragma unroll
            for (int v = 0; v < 4; ++v) {
                int r = m0 + (wm << 6) + (i << 4) + ((l >> 4) << 2) + v;
                float val = acc[i][j][v];
                if (XGT) {
                    int newr = ((col & 1023) << 2) | (col >> 10);   // j*4+g
                    ((float*)C)[(size_t)(r >> 6) * 262144 + (size_t)newr * 64 + (r & 63)] = val + bias;
                } else {
                    if (TANH) val = tanhf(val);
                    stout(&C[(size_t)r * N + col], val);
                }
            }
        }
    }
}

// ---------------------------------------------------------------------------
// One LSTM step, MFMA split-precision. Grid 128 x 256 thr (4 waves).
// Block owns 32 gate-rows (8 j x 4 g) x all 64 b. Wave = K-quarter.
// gates = Whi@hhi + Whi@hlo + Wlo@hhi (fp32-equivalent), + xgt; fused
// activation/state epilogue. c in [j][b] ws; h hand-off via bf16 hi/lo
// ping-pong buffers across launches (kernel boundary = coherence).
// ---------------------------------------------------------------------------
__global__ __launch_bounds__(256) void lstm_step3(
    const float* __restrict__ xgt,
    const u16* __restrict__ Whi, const u16* __restrict__ Wlo,
    const u16* __restrict__ hin_hi, const u16* __restrict__ hin_lo,
    u16* __restrict__ hout_hi, u16* __restrict__ hout_lo,
    float* __restrict__ c, u16* __restrict__ lstm16,
    float* __restrict__ hT, float* __restrict__ cT, int t)
{
    __shared__ float red[4][32 * 68];
    const int tid = threadIdx.x;
    const int kg = tid >> 6, l = tid & 63;
    const int tc = l & 15, tr8 = (l >> 4) << 3;
    const int r0 = blockIdx.x << 5;    // 32 rows
    const int j0 = blockIdx.x << 3;    // 8 j
    const int kbase = kg << 8;

    // early loads (independent of the GEMM): xgt gate values + running c
    float xgv[2][4], cv[2];
#pragma unroll
    for (int p = 0; p < 2; ++p) {
        int pid = tid + (p << 8);
        int j = pid >> 6, b = pid & 63;
#pragma unroll
        for (int g = 0; g < 4; ++g)
            xgv[p][g] = xgt[(size_t)t * 262144 + (size_t)((j0 + j) * 4 + g) * 64 + b];
        cv[p] = c[(size_t)(j0 + j) * 64 + b];
    }

    f32x4 acc[2][4] = {};
#pragma unroll 2
    for (int ks = 0; ks < 8; ++ks) {
        const int k = kbase + ks * 32 + tr8;
        bf16x8 ahi[2], alo[2], bhi[4], blo[4];
#pragma unroll
        for (int rt = 0; rt < 2; ++rt) {
            ahi[rt] = *(const bf16x8*)(Whi + (size_t)(r0 + rt * 16 + tc) * 1024 + k);
            alo[rt] = *(const bf16x8*)(Wlo + (size_t)(r0 + rt * 16 + tc) * 1024 + k);
        }
#pragma unroll
        for (int bt = 0; bt < 4; ++bt) {
            bhi[bt] = *(const bf16x8*)(hin_hi + (size_t)(bt * 16 + tc) * 1024 + k);
            blo[bt] = *(const bf16x8*)(hin_lo + (size_t)(bt * 16 + tc) * 1024 + k);
        }
#pragma unroll
        for (int rt = 0; rt < 2; ++rt)
#pragma unroll
            for (int bt = 0; bt < 4; ++bt) {
                acc[rt][bt] = __builtin_amdgcn_mfma_f32_16x16x32_bf16(ahi[rt], bhi[bt], acc[rt][bt], 0, 0, 0);
                acc[rt][bt] = __builtin_amdgcn_mfma_f32_16x16x32_bf16(ahi[rt], blo[bt], acc[rt][bt], 0, 0, 0);
                acc[rt][bt] = __builtin_amdgcn_mfma_f32_16x16x32_bf16(alo[rt], bhi[bt], acc[rt][bt], 0, 0, 0);
            }
    }
#pragma unroll
    for (int rt = 0; rt < 2; ++rt)
#pragma unroll
        for (int bt = 0; bt < 4; ++bt)
#pragma unroll
            for (int v = 0; v < 4; ++v)
                red[kg][(rt * 16 + (l >> 4) * 4 + v) * 68 + bt * 16 + tc] = acc[rt][bt][v];
    __syncthreads();

#pragma unroll
    for (int p = 0; p < 2; ++p) {
        int pid = tid + (p << 8);
        int j = pid >> 6, b = pid & 63;
        float gate[4];
#pragma unroll
        for (int g = 0; g < 4; ++g) {
            int rr = j * 4 + g;
            gate[g] = red[0][rr * 68 + b] + red[1][rr * 68 + b] +
                      red[2][rr * 68 + b] + red[3][rr * 68 + b] + xgv[p][g];
        }
        float ii = sigmoidf_(gate[0]);
        float ff = sigmoidf_(gate[1]);
        float gg = tanhf(gate[2]);
        float oo = sigmoidf_(gate[3]);
        float cn = ff * cv[p] + ii * gg;
        float hn = oo * tanhf(cn);
        c[(size_t)(j0 + j) * 64 + b] = cn;
        u16 hhi = f2bf(hn);
        u16 hlo = f2bf(hn - b2f(hhi));
        hout_hi[(size_t)b * 1024 + j0 + j] = hhi;
        hout_lo[(size_t)b * 1024 + j0 + j] = hlo;
        lstm16[((size_t)b * 128 + t) * 1024 + j0 + j] = hhi;
        if (t == 127) {
            hT[(size_t)b * 1024 + j0 + j] = hn;
            cT[(size_t)b * 1024 + j0 + j] = cn;
        }
    }
}

// ---------------------------------------------------------------------------
// fp32 GEMM C = A @ B^T (scores), batched via blockIdx.z.
// ---------------------------------------------------------------------------
template <int BM, int BN, int TM, int TN>
__global__ __launch_bounds__(256) void gemm_bt(
    const float* __restrict__ A, const float* __restrict__ Bm, float* __restrict__ C,
    int M, int N, int K, long sA, long sB, long sC)
{
    constexpr int BK = 16;
    __shared__ float As[BK][BM + 1];
    __shared__ float Bs[BK][BN + 1];
    const int z = blockIdx.z;
    A += (long)z * sA; Bm += (long)z * sB; C += (long)z * sC;
    const int bm = blockIdx.y * BM, bn = blockIdx.x * BN;
    const int tid = threadIdx.x;
    constexpr int TC = BN / TN;
    const int tc = tid % TC, tr = tid / TC;
    float acc[TM][TN] = {};
    for (int k0 = 0; k0 < K; k0 += BK) {
        for (int i = tid; i < BM * 4; i += 256) {
            int m = i >> 2, k4 = (i & 3) << 2;
            float4 v = *(const float4*)(A + (long)(bm + m) * K + k0 + k4);
            As[k4][m] = v.x; As[k4 + 1][m] = v.y; As[k4 + 2][m] = v.z; As[k4 + 3][m] = v.w;
        }
        for (int i = tid; i < BN * 4; i += 256) {
            int n = i >> 2, k4 = (i & 3) << 2;
            float4 v = *(const float4*)(Bm + (long)(bn + n) * K + k0 + k4);
            Bs[k4][n] = v.x; Bs[k4 + 1][n] = v.y; Bs[k4 + 2][n] = v.z; Bs[k4 + 3][n] = v.w;
        }
        __syncthreads();
#pragma unroll
        for (int kk = 0; kk < BK; ++kk) {
            float a[TM], b[TN];
#pragma unroll
            for (int i = 0; i < TM; i++) a[i] = As[kk][tr * TM + i];
#pragma unroll
            for (int j = 0; j < TN; j++) b[j] = Bs[kk][tc * TN + j];
#pragma unroll
            for (int i = 0; i < TM; i++)
#pragma unroll
                for (int j = 0; j < TN; j++) acc[i][j] += a[i] * b[j];
        }
        __syncthreads();
    }
#pragma unroll
    for (int i = 0; i < TM; i++) {
        int m = bm + tr * TM + i;
#pragma unroll
        for (int j = 0; j < TN; j++) {
            int n = bn + tc * TN + j;
            C[(long)m * N + n] = acc[i][j];
        }
    }
}

// ---------------------------------------------------------------------------
// fp32 GEMM C = A @ B (context = attn @ ctx), OT output.
// ---------------------------------------------------------------------------
template <int BM, int BN, int TM, int TN, typename OT>
__global__ __launch_bounds__(256) void gemm_bn(
    const float* __restrict__ A, const float* __restrict__ Bm, OT* __restrict__ C,
    int M, int N, int K, long sA, long sB, long sC)
{
    constexpr int BK = 16;
    __shared__ float As[BK][BM + 1];
    __shared__ float Bs[BK][BN + 1];
    const int z = blockIdx.z;
    A += (long)z * sA; Bm += (long)z * sB; C += (long)z * sC;
    const int bm = blockIdx.y * BM, bn = blockIdx.x * BN;
    const int tid = threadIdx.x;
    constexpr int TC = BN / TN;
    const int tc = tid % TC, tr = tid / TC;
    float acc[TM][TN] = {};
    for (int k0 = 0; k0 < K; k0 += BK) {
        for (int i = tid; i < BM * 4; i += 256) {
            int m = i >> 2, k4 = (i & 3) << 2;
            float4 v = *(const float4*)(A + (long)(bm + m) * K + k0 + k4);
            As[k4][m] = v.x; As[k4 + 1][m] = v.y; As[k4 + 2][m] = v.z; As[k4 + 3][m] = v.w;
        }
        for (int i = tid; i < BK * (BN / 4); i += 256) {
            int k = i / (BN / 4), n4 = (i % (BN / 4)) * 4;
            float4 v = *(const float4*)(Bm + (long)(k0 + k) * N + bn + n4);
            Bs[k][n4] = v.x; Bs[k][n4 + 1] = v.y; Bs[k][n4 + 2] = v.z; Bs[k][n4 + 3] = v.w;
        }
        __syncthreads();
#pragma unroll
        for (int kk = 0; kk < BK; ++kk) {
            float a[TM], b[TN];
#pragma unroll
            for (int i = 0; i < TM; i++) a[i] = As[kk][tr * TM + i];
#pragma unroll
            for (int j = 0; j < TN; j++) b[j] = Bs[kk][tc * TN + j];
#pragma unroll
            for (int i = 0; i < TM; i++)
#pragma unroll
                for (int j = 0; j < TN; j++) acc[i][j] += a[i] * b[j];
        }
        __syncthreads();
    }
#pragma unroll
    for (int i = 0; i < TM; i++) {
        int m = bm + tr * TM + i;
#pragma unroll
        for (int j = 0; j < TN; j++) {
            int n = bn + tc * TN + j;
            stout(&C[(long)m * N + n], acc[i][j]);
        }
    }
}

// ---------------------------------------------------------------------------
// Masked softmax over S=256, in place.
// ---------------------------------------------------------------------------
__global__ __launch_bounds__(256) void softmax_mask(
    float* __restrict__ attn, const int* __restrict__ src_len)
{
    __shared__ float red[4];
    const int b = blockIdx.y, t = blockIdx.x, s = threadIdx.x;
    float* row = attn + ((long)b * TT + t) * SS;
    const int L = src_len[b];
    float v = (s < L) ? row[s] : -INFINITY;
    float m = v;
#pragma unroll
    for (int o = 32; o >= 1; o >>= 1) m = fmaxf(m, __shfl_xor(m, o));
    if ((s & 63) == 0) red[s >> 6] = m;
    __syncthreads();
    m = fmaxf(fmaxf(red[0], red[1]), fmaxf(red[2], red[3]));
    __syncthreads();
    float e = (s < L) ? expf(v - m) : 0.0f;
    float sum = e;
#pragma unroll
    for (int o = 32; o >= 1; o >>= 1) sum += __shfl_xor(sum, o);
    if ((s & 63) == 0) red[s >> 6] = sum;
    __syncthreads();
    sum = red[0] + red[1] + red[2] + red[3];
    row[s] = e / sum;
}

// ---------------------------------------------------------------------------
extern "C" void kernel_launch(void* const* d_in, const int* in_sizes, int n_in,
                              void* d_out, int out_size, void* d_ws, size_t ws_size,
                              hipStream_t stream)
{
    const float* trg_emb = (const float*)d_in[0];
    const float* h0      = (const float*)d_in[1];
    const float* c0      = (const float*)d_in[2];
    const float* ctx     = (const float*)d_in[3];
    const int*   src_len = (const int*)d_in[4];
    const float* W_ih    = (const float*)d_in[5];
    const float* W_hh    = (const float*)d_in[6];
    const float* b_ih    = (const float*)d_in[7];
    const float* b_hh    = (const float*)d_in[8];
    const float* W_in    = (const float*)d_in[9];
    const float* W_out   = (const float*)d_in[10];

    float* out = (float*)d_out;
    float* h_tilde = out;                          // [B,T,H]
    float* hT = out + (size_t)BB * TT * HHH;       // [1,B,H]
    float* cT = hT + (size_t)BB * HHH;             // [1,B,H]

    char* w = (char*)d_ws;
    auto take = [&](size_t bytes) { void* p = w; w += (bytes + 255) & ~(size_t)255; return p; };
    u16* trg16  = (u16*)take(8388608ull * 2);
    u16* Wih16  = (u16*)take(4194304ull * 2);
    u16* Win16  = (u16*)take(1048576ull * 2);
    u16* Wout16 = (u16*)take(2097152ull * 2);
    u16* lstm16 = (u16*)take(8388608ull * 2);
    u16* Whi    = (u16*)take(4194304ull * 2);
    u16* Wlo    = (u16*)take(4194304ull * 2);
    u16* hEhi   = (u16*)take(65536ull * 2);
    u16* hElo   = (u16*)take(65536ull * 2);
    u16* hOhi   = (u16*)take(65536ull * 2);
    u16* hOlo   = (u16*)take(65536ull * 2);
    float* cws  = (float*)take(65536ull * 4);
    char* regionB = w;
    float* xgt = (float*)take(33554432ull * 4);    // [t][4H r=j*4+g][B] fp32
    float* q        = (float*)regionB;
    float* attn     = (float*)(regionB + 33554432ull);
    u16*   ctxout16 = (u16*)(regionB + 41943040ull);

    // prep (independent, parallel)
    f32_to_bf16<<<4096, 256, 0, stream>>>(trg_emb, trg16, 8388608);
    f32_to_bf16<<<2048, 256, 0, stream>>>(W_ih, Wih16, 4194304);
    f32_to_bf16<<<512, 256, 0, stream>>>(W_in, Win16, 1048576);
    f32_to_bf16<<<1024, 256, 0, stream>>>(W_out, Wout16, 2097152);
    split_whh<<<4096, 256, 0, stream>>>(W_hh, Whi, Wlo);
    h0_split<<<64, 256, 0, stream>>>(h0, hEhi, hElo);
    transpose_c0<<<256, 256, 0, stream>>>(c0, cws);

    // x_gates = trg_emb @ W_ih^T + (b_ih+b_hh) -> fp32 xgt[t][j*4+g][b]
    gemm_mfma_bt<false, true, float><<<dim3(32, 64), 256, 0, stream>>>(
        trg16, trg16, Wih16, xgt, 8192, 4096, 1024, 1024, b_ih, b_hh);

    // LSTM scan: 128 launches (kernel boundary = cross-XCD coherence)
    for (int t = 0; t < TT; ++t) {
        const u16* ihi = (t & 1) ? hOhi : hEhi;
        const u16* ilo = (t & 1) ? hOlo : hElo;
        u16* ohi = (t & 1) ? hEhi : hOhi;
        u16* olo = (t & 1) ? hElo : hOlo;
        lstm_step3<<<128, 256, 0, stream>>>(xgt, Whi, Wlo, ihi, ilo, ohi, olo,
                                            cws, lstm16, hT, cT, t);
    }

    // q = lstm_out @ W_in^T (bf16 MFMA, fp32 out)
    gemm_mfma_bt<false, false, float><<<dim3(8, 64), 256, 0, stream>>>(
        lstm16, lstm16, Win16, q, 8192, 1024, 1024, 1024, nullptr, nullptr);

    // scores[b] = q[b] @ ctx[b]^T (fp32)
    gemm_bt<64, 64, 4, 4><<<dim3(4, 2, 64), 256, 0, stream>>>(
        q, ctx, attn, TT, SS, HHH,
        (long)TT * HHH, (long)SS * HHH, (long)TT * SS);

    softmax_mask<<<dim3(TT, BB, 1), 256, 0, stream>>>(attn, src_len);

    // context[b] = attn[b] @ ctx[b] (fp32 compute, bf16 out)
    gemm_bn<64, 64, 4, 4, u16><<<dim3(16, 2, 64), 256, 0, stream>>>(
        attn, ctx, ctxout16, TT, HHH, SS,
        (long)TT * SS, (long)SS * HHH, (long)TT * HHH);

    // h_tilde = tanh([context, lstm_out] @ W_out^T)
    gemm_mfma_bt<true, false, float><<<dim3(8, 64), 256, 0, stream>>>(
        ctxout16, lstm16, Wout16, h_tilde, 8192, 1024, 2048, 1024, nullptr, nullptr);
}